// Round 1
// baseline (407.084 us; speedup 1.0000x reference)
//
#include <hip/hip_runtime.h>

// Problem constants (B=8192, S=32, N=128, K=64, M=3)
#define BATCH 8192
#define EPSF 1e-9f

// One block per batch b.
// Phase A: C_p[s][j] = sum_k x[b][s][k] * P[b][k][j]   (32x64 = x(32x64) @ P(64x64))
//   wave w handles rows 8w..8w+7; lane j = column j; x broadcast via uniform
//   float4 global loads (one 16B request/wave, L1/L2 served), P from LDS stride-1.
// Phase B: top-4 of |[x_row | C_p_row]| (128 vals) -> hm = t0/(t3+eps)
//   8 threads/row, 16 vals each, insertion top-4 + 3 bitonic merge levels.
// Then max over 32 rows, relu(max_hm - y_pred[b]), atomicAdd; log-MSE term too.
__global__ __launch_bounds__(256) void avl_main(
    const float* __restrict__ y_pred,
    const float* __restrict__ y_true,
    const float* __restrict__ P,   // [B][64][64]
    const float* __restrict__ X,   // [B][32][64]
    float* __restrict__ accum)     // accum[0]=violation sum, accum[1]=logmse sum
{
    __shared__ float P_lds[64 * 64];   // 16 KB
    __shared__ float C_lds[32 * 64];   // 8 KB, |x@P| part
    __shared__ float hm_lds[32];

    const int b   = blockIdx.x;
    const int tid = threadIdx.x;

    // ---- stage P[b] into LDS (coalesced float4) ----
    const float4* Pg = (const float4*)(P + (size_t)b * 4096);
    float4* Pl = (float4*)P_lds;
#pragma unroll
    for (int i = 0; i < 4; ++i) Pl[tid + 256 * i] = Pg[tid + 256 * i];
    __syncthreads();

    // ---- phase A: matmul ----
    const int wave = tid >> 6;
    const int lane = tid & 63;
    const int r0   = wave * 8;
    const float* xbase = X + (size_t)b * 2048 + r0 * 64;

    float acc0 = 0.f, acc1 = 0.f, acc2 = 0.f, acc3 = 0.f;
    float acc4 = 0.f, acc5 = 0.f, acc6 = 0.f, acc7 = 0.f;

    for (int k = 0; k < 64; k += 4) {
        float4 xv[8];
#pragma unroll
        for (int r = 0; r < 8; ++r)
            xv[r] = *(const float4*)(xbase + r * 64 + k);
        const float p0 = P_lds[(k + 0) * 64 + lane];
        const float p1 = P_lds[(k + 1) * 64 + lane];
        const float p2 = P_lds[(k + 2) * 64 + lane];
        const float p3 = P_lds[(k + 3) * 64 + lane];
#define STEP(A, R)                                     \
        A = fmaf(xv[R].x, p0, A);                      \
        A = fmaf(xv[R].y, p1, A);                      \
        A = fmaf(xv[R].z, p2, A);                      \
        A = fmaf(xv[R].w, p3, A);
        STEP(acc0, 0) STEP(acc1, 1) STEP(acc2, 2) STEP(acc3, 3)
        STEP(acc4, 4) STEP(acc5, 5) STEP(acc6, 6) STEP(acc7, 7)
#undef STEP
    }
    C_lds[(r0 + 0) * 64 + lane] = fabsf(acc0);
    C_lds[(r0 + 1) * 64 + lane] = fabsf(acc1);
    C_lds[(r0 + 2) * 64 + lane] = fabsf(acc2);
    C_lds[(r0 + 3) * 64 + lane] = fabsf(acc3);
    C_lds[(r0 + 4) * 64 + lane] = fabsf(acc4);
    C_lds[(r0 + 5) * 64 + lane] = fabsf(acc5);
    C_lds[(r0 + 6) * 64 + lane] = fabsf(acc6);
    C_lds[(r0 + 7) * 64 + lane] = fabsf(acc7);
    __syncthreads();

    // ---- phase B: top-4 selection per row ----
    const int row = tid >> 3;   // 0..31
    const int sub = tid & 7;    // 0..7  (8 threads per row)

    // 16 candidates: 8 from identity part |x|, 8 from |x@P|
    const float* xr = X + (size_t)b * 2048 + row * 64 + sub * 8;
    float4 a0 = *(const float4*)(xr);
    float4 a1 = *(const float4*)(xr + 4);
    const float* cr = C_lds + row * 64 + sub * 8;
    float4 c0 = *(const float4*)(cr);
    float4 c1 = *(const float4*)(cr + 4);

    float vals[16] = {
        fabsf(a0.x), fabsf(a0.y), fabsf(a0.z), fabsf(a0.w),
        fabsf(a1.x), fabsf(a1.y), fabsf(a1.z), fabsf(a1.w),
        c0.x, c0.y, c0.z, c0.w, c1.x, c1.y, c1.z, c1.w
    };

    float t0 = -1.f, t1 = -1.f, t2 = -1.f, t3 = -1.f;
#pragma unroll
    for (int i = 0; i < 16; ++i) {
        float v = vals[i];
        float m;
        m = fminf(t0, v); t0 = fmaxf(t0, v); v = m;
        m = fminf(t1, v); t1 = fmaxf(t1, v); v = m;
        m = fminf(t2, v); t2 = fmaxf(t2, v); v = m;
        t3 = fmaxf(t3, v);
    }

    // merge across the 8 sub-lanes (xor 1,2,4): bitonic top-4 merge
#pragma unroll
    for (int msk = 1; msk <= 4; msk <<= 1) {
        float b0 = __shfl_xor(t0, msk, 64);
        float b1 = __shfl_xor(t1, msk, 64);
        float b2 = __shfl_xor(t2, msk, 64);
        float b3 = __shfl_xor(t3, msk, 64);
        // top-4 set of two desc-sorted lists (bitonic first stage)
        float c0v = fmaxf(t0, b3);
        float c1v = fmaxf(t1, b2);
        float c2v = fmaxf(t2, b1);
        float c3v = fmaxf(t3, b0);
        // sort the bitonic 4-seq descending
        float d0 = fmaxf(c0v, c2v), d2 = fminf(c0v, c2v);
        float d1 = fmaxf(c1v, c3v), d3 = fminf(c1v, c3v);
        t0 = fmaxf(d0, d1); t1 = fminf(d0, d1);
        t2 = fmaxf(d2, d3); t3 = fminf(d2, d3);
    }

    if (sub == 0) hm_lds[row] = t0 / (t3 + EPSF);
    __syncthreads();

    // ---- block reduce: max hm over 32 rows, then the two loss terms ----
    if (tid < 32) {
        float h = hm_lds[tid];
#pragma unroll
        for (int msk = 16; msk >= 1; msk >>= 1)
            h = fmaxf(h, __shfl_xor(h, msk, 64));
        if (tid == 0) {
            float yp = y_pred[b];
            float pen = fmaxf(h - yp, 0.f);
            atomicAdd(&accum[0], pen);
            float lp = log2f(fmaxf(yp, EPSF));
            float lt = log2f(fmaxf(y_true[b], EPSF));
            float d = lt - lp;
            atomicAdd(&accum[1], d * d);
        }
    }
}

__global__ void avl_final(const float* __restrict__ accum, float* __restrict__ out)
{
    const float vi = accum[0] * (1.0f / (float)BATCH);
    const float lm = accum[1] * (1.0f / (float)BATCH);
    out[0] = lm + 0.5f * vi;   // total_loss
    out[1] = lm;               // loss_logmse
    out[2] = vi;               // loss_violation
}

extern "C" void kernel_launch(void* const* d_in, const int* in_sizes, int n_in,
                              void* d_out, int out_size, void* d_ws, size_t ws_size,
                              hipStream_t stream)
{
    const float* y_pred = (const float*)d_in[0];
    const float* y_true = (const float*)d_in[1];
    const float* P      = (const float*)d_in[2];
    const float* X      = (const float*)d_in[3];
    // d_in[4] (params) is constant metadata; unused.

    float* accum = (float*)d_ws;
    hipMemsetAsync(accum, 0, 2 * sizeof(float), stream);
    avl_main<<<BATCH, 256, 0, stream>>>(y_pred, y_true, P, X, accum);
    avl_final<<<1, 1, 0, stream>>>(accum, (float*)d_out);
}

// Round 2
// 398.308 us; speedup vs baseline: 1.0220x; 1.0220x over previous
//
#include <hip/hip_runtime.h>

// Problem constants (B=8192, S=32, N=128, K=64, M=3)
#define BATCH 8192
#define EPSF 1e-9f

// Broadcast a register value from a compile-time lane (VALU, no DS pipe).
__device__ __forceinline__ float rl(float v, int lane) {
    return __int_as_float(__builtin_amdgcn_readlane(__float_as_int(v), lane));
}

// One block per batch b.
// Phase A: C_p = x(32x64) @ P(64x64). Wave w owns rows 8w..8w+7, lane j = col j.
//   x fragment distributed across lanes (lane L: row r0+(L>>3), cols (L&7)*8..+7),
//   loaded from global ONCE (coalesced), broadcast via v_readlane in the k-loop.
//   P read from LDS stride-1 (2-way bank aliasing = free).
// Phase B: top-4 of |[x_row | C_p_row]| -> hm = t0/(t3+eps); x part comes straight
//   from the phase-A register fragment (mappings coincide).
__global__ __launch_bounds__(256) void avl_main(
    const float* __restrict__ y_pred,
    const float* __restrict__ y_true,
    const float* __restrict__ P,   // [B][64][64]
    const float* __restrict__ X,   // [B][32][64]
    float* __restrict__ accum)     // accum[0]=violation sum, accum[1]=logmse sum
{
    __shared__ float P_lds[64 * 64];   // 16 KB
    __shared__ float C_lds[32 * 64];   // 8 KB, |x@P| part
    __shared__ float hm_lds[32];

    const int b   = blockIdx.x;
    const int tid = threadIdx.x;

    // ---- stage P[b] into LDS (coalesced float4) ----
    const float4* Pg = (const float4*)(P + (size_t)b * 4096);
    float4* Pl = (float4*)P_lds;
#pragma unroll
    for (int i = 0; i < 4; ++i) Pl[tid + 256 * i] = Pg[tid + 256 * i];

    // ---- load x fragment (while P staging is in flight) ----
    const int wave = tid >> 6;
    const int lane = tid & 63;
    const int r0   = wave * 8;
    const float* xsrc = X + (size_t)b * 2048 + (r0 + (lane >> 3)) * 64 + (lane & 7) * 8;
    const float4 xf0 = *(const float4*)(xsrc);
    const float4 xf1 = *(const float4*)(xsrc + 4);
    float xf[8] = { xf0.x, xf0.y, xf0.z, xf0.w, xf1.x, xf1.y, xf1.z, xf1.w };

    __syncthreads();

    // ---- phase A: matmul, fully unrolled k ----
    float acc[8] = { 0.f, 0.f, 0.f, 0.f, 0.f, 0.f, 0.f, 0.f };
#pragma unroll
    for (int k = 0; k < 64; ++k) {
        const float p = P_lds[k * 64 + lane];
        const int src8 = k >> 3;   // which lane-subgroup holds this k
        const int reg  = k & 7;    // which fragment register
#pragma unroll
        for (int r = 0; r < 8; ++r) {
            const float xv = rl(xf[reg], r * 8 + src8);
            acc[r] = fmaf(xv, p, acc[r]);
        }
    }
#pragma unroll
    for (int r = 0; r < 8; ++r)
        C_lds[(r0 + r) * 64 + lane] = fabsf(acc[r]);
    __syncthreads();

    // ---- phase B: top-4 selection per row ----
    // thread mapping (row = tid>>3, sub = tid&7) coincides with the phase-A
    // fragment mapping, so the identity-part |x| values are xf[] directly.
    const int row = tid >> 3;   // 0..31
    const int sub = tid & 7;    // 0..7

    const float* cr = C_lds + row * 64 + sub * 8;
    const float4 c0 = *(const float4*)(cr);
    const float4 c1 = *(const float4*)(cr + 4);

    float vals[16] = {
        fabsf(xf[0]), fabsf(xf[1]), fabsf(xf[2]), fabsf(xf[3]),
        fabsf(xf[4]), fabsf(xf[5]), fabsf(xf[6]), fabsf(xf[7]),
        c0.x, c0.y, c0.z, c0.w, c1.x, c1.y, c1.z, c1.w
    };

    float t0 = -1.f, t1 = -1.f, t2 = -1.f, t3 = -1.f;
#pragma unroll
    for (int i = 0; i < 16; ++i) {
        float v = vals[i];
        float m;
        m = fminf(t0, v); t0 = fmaxf(t0, v); v = m;
        m = fminf(t1, v); t1 = fmaxf(t1, v); v = m;
        m = fminf(t2, v); t2 = fmaxf(t2, v); v = m;
        t3 = fmaxf(t3, v);
    }

    // merge across the 8 sub-lanes (xor 1,2,4): bitonic top-4 merge
#pragma unroll
    for (int msk = 1; msk <= 4; msk <<= 1) {
        float b0 = __shfl_xor(t0, msk, 64);
        float b1 = __shfl_xor(t1, msk, 64);
        float b2 = __shfl_xor(t2, msk, 64);
        float b3 = __shfl_xor(t3, msk, 64);
        float c0v = fmaxf(t0, b3);
        float c1v = fmaxf(t1, b2);
        float c2v = fmaxf(t2, b1);
        float c3v = fmaxf(t3, b0);
        float d0 = fmaxf(c0v, c2v), d2 = fminf(c0v, c2v);
        float d1 = fmaxf(c1v, c3v), d3 = fminf(c1v, c3v);
        t0 = fmaxf(d0, d1); t1 = fminf(d0, d1);
        t2 = fmaxf(d2, d3); t3 = fminf(d2, d3);
    }

    if (sub == 0) hm_lds[row] = t0 / (t3 + EPSF);
    __syncthreads();

    // ---- block reduce: max hm over 32 rows, then the two loss terms ----
    if (tid < 32) {
        float h = hm_lds[tid];
#pragma unroll
        for (int msk = 16; msk >= 1; msk >>= 1)
            h = fmaxf(h, __shfl_xor(h, msk, 64));
        if (tid == 0) {
            float yp = y_pred[b];
            float pen = fmaxf(h - yp, 0.f);
            atomicAdd(&accum[0], pen);
            float lp = log2f(fmaxf(yp, EPSF));
            float lt = log2f(fmaxf(y_true[b], EPSF));
            float d = lt - lp;
            atomicAdd(&accum[1], d * d);
        }
    }
}

__global__ void avl_final(const float* __restrict__ accum, float* __restrict__ out)
{
    const float vi = accum[0] * (1.0f / (float)BATCH);
    const float lm = accum[1] * (1.0f / (float)BATCH);
    out[0] = lm + 0.5f * vi;   // total_loss
    out[1] = lm;               // loss_logmse
    out[2] = vi;               // loss_violation
}

extern "C" void kernel_launch(void* const* d_in, const int* in_sizes, int n_in,
                              void* d_out, int out_size, void* d_ws, size_t ws_size,
                              hipStream_t stream)
{
    const float* y_pred = (const float*)d_in[0];
    const float* y_true = (const float*)d_in[1];
    const float* P      = (const float*)d_in[2];
    const float* X      = (const float*)d_in[3];

    float* accum = (float*)d_ws;
    hipMemsetAsync(accum, 0, 2 * sizeof(float), stream);
    avl_main<<<BATCH, 256, 0, stream>>>(y_pred, y_true, P, X, accum);
    avl_final<<<1, 1, 0, stream>>>(accum, (float*)d_out);
}